// Round 3
// baseline (229.942 us; speedup 1.0000x reference)
//
#include <hip/hip_runtime.h>
#include <math.h>

// FraudDetectionNet: per-2x2-patch 4-qubit circuit -> Z expectations -> linear -> sigmoid.
// - 2 horizontally-adjacent patches per thread (float4 row loads, amortized overhead)
// - first two identical RY layers folded into double-angle product-state init
// - single fused kernel: segmented wave reduce -> wsum, last block (atomic ticket)
//   gathers per-image partials, adds bias, sigmoid.

#define B_IMG    8192
#define PAIRS_PI 98                      // 196 patches / 2 per image
#define NPAIR    (B_IMG * PAIRS_PI)     // 802,816 = 3136 * 256
#define NWAVE    (NPAIR / 64)           // 12,544
#define NBLOCK   (NPAIR / 256)          // 3,136

__device__ __forceinline__ float sim_patch(const float pv0, const float pv1,
                                           const float pv2, const float pv3,
                                           const float4 w4) {
    const float pv[4] = { pv0, pv1, pv2, pv3 };
    // half-angle = clip(p,-1,1)*pi/2 ; hw trig in revolutions: r = t*0.25
    float ch[4], sh[4], c2[4], s2[4];
    #pragma unroll
    for (int q = 0; q < 4; ++q) {
        const float t = fminf(fmaxf(pv[q], -1.0f), 1.0f);
        const float r = t * 0.25f;
        sh[q] = __builtin_amdgcn_sinf(r);              // sin(t*pi/2)
        ch[q] = __builtin_amdgcn_cosf(r);              // cos(t*pi/2)
        const float tm = sh[q] + sh[q];
        c2[q] = fmaf(-tm, sh[q], 1.0f);                // cos(t*pi)
        s2[q] = tm * ch[q];                            // sin(t*pi)
    }

    // Product state after two fused RY layers (double angle).
    float st[16];
    {
        const float hi[4] = { c2[0]*c2[1], c2[0]*s2[1], s2[0]*c2[1], s2[0]*s2[1] };
        const float lo[4] = { c2[2]*c2[3], c2[2]*s2[3], s2[2]*c2[3], s2[2]*s2[3] };
        #pragma unroll
        for (int h = 0; h < 4; ++h)
            #pragma unroll
            for (int l = 0; l < 4; ++l)
                st[h * 4 + l] = hi[h] * lo[l];
    }

    // CNOT(0,1): b3 set -> b ^= 4 ; CNOT(2,3): b1 set -> b ^= 1  (register renames)
    #pragma unroll
    for (int k = 0; k < 4; ++k) { const float t = st[8+k]; st[8+k] = st[12+k]; st[12+k] = t; }
    { float t;
      t = st[2];  st[2]  = st[3];  st[3]  = t;
      t = st[6];  st[6]  = st[7];  st[7]  = t;
      t = st[10]; st[10] = st[11]; st[11] = t;
      t = st[14]; st[14] = st[15]; st[15] = t; }

    // 2 remaining [RY layer + CNOTs] with half-angle (ch, sh)
    #pragma unroll
    for (int layer = 0; layer < 2; ++layer) {
        #pragma unroll
        for (int q = 0; q < 4; ++q) {
            const int m = 8 >> q;
            #pragma unroll
            for (int b = 0; b < 16; ++b) {
                if (b & m) continue;
                const float a0 = st[b];
                const float a1 = st[b | m];
                st[b]     = ch[q] * a0 - sh[q] * a1;
                st[b | m] = sh[q] * a0 + ch[q] * a1;
            }
        }
        #pragma unroll
        for (int k = 0; k < 4; ++k) { const float t = st[8+k]; st[8+k] = st[12+k]; st[12+k] = t; }
        { float t;
          t = st[2];  st[2]  = st[3];  st[3]  = t;
          t = st[6];  st[6]  = st[7];  st[7]  = t;
          t = st[10]; st[10] = st[11]; st[11] = t;
          t = st[14]; st[14] = st[15]; st[15] = t; }
    }

    // sum_b st[b]^2 * coef[b];  coef[b] = +-w0 +-w1 +-w2 +-w3 per bits
    float e01[4], e23[4];
    e01[0] =  w4.x + w4.y;  e01[1] =  w4.x - w4.y;
    e01[2] = -w4.x + w4.y;  e01[3] = -w4.x - w4.y;
    e23[0] =  w4.z + w4.w;  e23[1] =  w4.z - w4.w;
    e23[2] = -w4.z + w4.w;  e23[3] = -w4.z - w4.w;
    float partial = 0.0f;
    #pragma unroll
    for (int b = 0; b < 16; ++b)
        partial = fmaf(st[b] * st[b], e01[b >> 2] + e23[b & 3], partial);
    return partial;
}

__global__ __launch_bounds__(256) void fraud_fused(
    const float* __restrict__ x,     // (B,1,28,28)
    const float* __restrict__ W,     // (784,1)
    const float* __restrict__ bias,  // (1,)
    float* __restrict__ out,         // (B,)
    float2* __restrict__ wsum,       // (NWAVE)
    unsigned* __restrict__ counter)  // ticket (zeroed each launch)
{
    const int tid  = threadIdx.x;
    const int gtid = blockIdx.x * 256 + tid;
    const int lane = tid & 63;
    const int gw   = gtid >> 6;

    const unsigned P   = (unsigned)gtid;        // pair index
    const unsigned img = P / 98u;
    const unsigned pp  = P - img * 98u;         // pair within image
    const unsigned i   = pp / 7u;               // patch row (0..13)
    const unsigned jj  = pp - i * 7u;           // pair col (0..6)

    // two adjacent patches: cols 4jj..4jj+3 of rows 2i and 2i+1 (16B aligned)
    const float* rowp = x + (size_t)img * 784 + (2u * i) * 28 + 4u * jj;
    const float4 ra = *reinterpret_cast<const float4*>(rowp);
    const float4 rb = *reinterpret_cast<const float4*>(rowp + 28);
    const float4 wA = *reinterpret_cast<const float4*>(W + 8u * pp);
    const float4 wB = *reinterpret_cast<const float4*>(W + 8u * pp + 4);

    float partial = sim_patch(ra.x, ra.y, rb.x, rb.y, wA)
                  + sim_patch(ra.z, ra.w, rb.z, rb.w, wB);

    // Segmented wave reduce: 64 pairs span at most 2 images (64 < 98).
    const unsigned imgF = __shfl(img, 0, 64);
    float va = (img == imgF) ? partial : 0.0f;
    float vb = partial - va;
    #pragma unroll
    for (int off = 32; off > 0; off >>= 1) {
        va += __shfl_xor(va, off, 64);
        vb += __shfl_xor(vb, off, 64);
    }
    if (lane == 0) {
        wsum[gw] = make_float2(va, vb);
        __threadfence();                       // release: writes device-visible
    }
    __syncthreads();

    __shared__ int isLast;
    if (tid == 0)
        isLast = (atomicAdd(counter, 1u) == (unsigned)(gridDim.x - 1));
    __syncthreads();
    if (!isLast) return;

    __threadfence();                           // acquire
    const float bv = bias[0];
    for (unsigned im = (unsigned)tid; im < B_IMG; im += 256) {
        const unsigned lo = (im * 98u) >> 6;
        const unsigned hi = (im * 98u + 97u) >> 6;
        float acc = bv;
        for (unsigned w = lo; w <= hi; ++w) {  // <= 3 iterations
            const float2 s = wsum[w];
            const unsigned f = (w * 64u) / 98u;
            const unsigned l = (w * 64u + 63u) / 98u;
            if (f == im) acc += s.x;
            if (l == im && l != f) acc += s.y;
        }
        out[im] = 1.0f / (1.0f + __expf(-acc));
    }
}

extern "C" void kernel_launch(void* const* d_in, const int* in_sizes, int n_in,
                              void* d_out, int out_size, void* d_ws, size_t ws_size,
                              hipStream_t stream) {
    const float* x    = (const float*)d_in[0];
    const float* W    = (const float*)d_in[1];
    const float* bias = (const float*)d_in[2];
    float* out = (float*)d_out;

    float2* wsum = (float2*)d_ws;                                  // 100,352 B
    unsigned* counter = (unsigned*)((char*)d_ws + NWAVE * sizeof(float2));

    hipMemsetAsync(counter, 0, sizeof(unsigned), stream);          // graph-capturable
    fraud_fused<<<dim3(NBLOCK), dim3(256), 0, stream>>>(x, W, bias, out, wsum, counter);
}

// Round 4
// 15.443 us; speedup vs baseline: 14.8893x; 14.8893x over previous
//
#include <hip/hip_runtime.h>
#include <math.h>

// FraudDetectionNet: per-2x2-patch 4-qubit circuit -> Z expectations -> linear -> sigmoid.
//
// Key algebra: CNOT(0,1) and CNOT(2,3) never couple the pairs {q0,q1} x {q2,q3},
// so the 16-dim state is A (x) B with A,B 4-dim for the whole circuit. Per 2-qubit
// register: first two identical RY layers fold to a double-angle product init
// (RY(t)RY(t)=RY(2t)), CNOT = register swap (free), then 2 x [16-op RY layer + swap].
// Measurement: w0*z0 + w1*z1 = (p0-p3)(w0+w1) + (p1-p2)(w0-w1), p_i = A_i^2.
// ~124 VALU ops/patch -> memory-bound (25.7 MB input, ~4.1 us HBM floor).
//
// One 128-thread block per image: threads 0..97 each simulate one horizontal
// patch-pair (float4 row loads), butterfly wave reduce, LDS combine, sigmoid.
// Single launch; no cross-block communication (round-3 threadfence disaster:
// per-block device-scope release = L2 writeback per block = 230 us).

__device__ __forceinline__ float reg2(float t0, float t1, float w0, float w1) {
    // clip to [-1,1]; half-angle = t*pi/2 -> hw trig in revolutions r = t*0.25
    const float u0 = fminf(fmaxf(t0, -1.0f), 1.0f);
    const float u1 = fminf(fmaxf(t1, -1.0f), 1.0f);
    const float s0 = __builtin_amdgcn_sinf(u0 * 0.25f);
    const float c0 = __builtin_amdgcn_cosf(u0 * 0.25f);
    const float s1 = __builtin_amdgcn_sinf(u1 * 0.25f);
    const float c1 = __builtin_amdgcn_cosf(u1 * 0.25f);
    // double angles: cos(t*pi) = 1-2s^2, sin(t*pi) = 2sc
    const float c20 = fmaf(-2.0f * s0, s0, 1.0f);
    const float s20 = (s0 + s0) * c0;
    const float c21 = fmaf(-2.0f * s1, s1, 1.0f);
    const float s21 = (s1 + s1) * c1;

    // init (folded RY^2 product state) followed by CNOT (swap A2<->A3):
    float A0 = c20 * c21, A1 = c20 * s21, A2 = s20 * s21, A3 = s20 * c21;

    // 2 x [RY(t) layer on both wires, CNOT]
    #pragma unroll
    for (int l = 0; l < 2; ++l) {
        // wire0 (c0,s0): pairs (A0,A2),(A1,A3)
        const float n0 = c0 * A0 - s0 * A2;
        const float n2 = s0 * A0 + c0 * A2;
        const float n1 = c0 * A1 - s0 * A3;
        const float n3 = s0 * A1 + c0 * A3;
        // wire1 (c1,s1): pairs (n0,n1),(n2,n3)
        A0 = c1 * n0 - s1 * n1;
        A1 = s1 * n0 + c1 * n1;
        A2 = c1 * n2 - s1 * n3;
        A3 = s1 * n2 + c1 * n3;
        // CNOT: swap A2<->A3 (free rename)
        const float tt = A2; A2 = A3; A3 = tt;
    }

    const float p0 = A0 * A0, p1 = A1 * A1, p2 = A2 * A2, p3 = A3 * A3;
    return (p0 - p3) * (w0 + w1) + (p1 - p2) * (w0 - w1);
}

__device__ __forceinline__ float sim_patch(float t0, float t1, float t2, float t3,
                                           const float4 w) {
    // wires (0,1) <- row0 pixels, wires (2,3) <- row1 pixels
    return reg2(t0, t1, w.x, w.y) + reg2(t2, t3, w.z, w.w);
}

__global__ __launch_bounds__(128) void fraud_kernel(
    const float* __restrict__ x,     // (B,1,28,28)
    const float* __restrict__ W,     // (784,1)
    const float* __restrict__ bias,  // (1,)
    float* __restrict__ out)         // (B,)
{
    const int tid = threadIdx.x;
    const unsigned img = blockIdx.x;

    const unsigned pp = (tid < 98) ? (unsigned)tid : 0u;  // pair index 0..97
    const unsigned i  = pp / 7u;                          // patch row 0..13
    const unsigned jj = pp - i * 7u;                      // pair col 0..6

    // two adjacent patches: rows 2i,2i+1, cols 4jj..4jj+3 (16B-aligned)
    const float* rowp = x + (size_t)img * 784 + (2u * i) * 28 + 4u * jj;
    const float4 ra = *reinterpret_cast<const float4*>(rowp);
    const float4 rb = *reinterpret_cast<const float4*>(rowp + 28);
    const float4 wA = *reinterpret_cast<const float4*>(W + 8u * pp);
    const float4 wB = *reinterpret_cast<const float4*>(W + 8u * pp + 4);

    float partial = sim_patch(ra.x, ra.y, rb.x, rb.y, wA)
                  + sim_patch(ra.z, ra.w, rb.z, rb.w, wB);
    if (tid >= 98) partial = 0.0f;

    // wave butterfly + 2-slot LDS combine
    #pragma unroll
    for (int off = 32; off > 0; off >>= 1)
        partial += __shfl_xor(partial, off, 64);

    __shared__ float red[2];
    if ((tid & 63) == 0) red[tid >> 6] = partial;
    __syncthreads();

    if (tid == 0) {
        const float v = red[0] + red[1] + bias[0];
        out[img] = 1.0f / (1.0f + __expf(-v));
    }
}

extern "C" void kernel_launch(void* const* d_in, const int* in_sizes, int n_in,
                              void* d_out, int out_size, void* d_ws, size_t ws_size,
                              hipStream_t stream) {
    const float* x    = (const float*)d_in[0];
    const float* W    = (const float*)d_in[1];
    const float* bias = (const float*)d_in[2];
    float* out = (float*)d_out;

    const int B = out_size;  // 8192
    fraud_kernel<<<dim3(B), dim3(128), 0, stream>>>(x, W, bias, out);
}